// Round 1
// baseline (1797.520 us; speedup 1.0000x reference)
//
#include <hip/hip_runtime.h>
#include <hip/hip_bf16.h>

typedef __hip_bfloat16 bf16;

static __device__ __forceinline__ float b2f(bf16 v) { return __bfloat162float(v); }
static __device__ __forceinline__ bf16 f2b(float v) { return __float2bfloat16(v); }

// ---------------- preprocessing ----------------

__global__ void k_init(int* ecnt, int* cnt, int n) {
  int i = blockIdx.x * blockDim.x + threadIdx.x;
  if (i < n) { ecnt[i] = 0; cnt[i] = 0; }
}

__global__ void k_hist(const int* dst, int e, int* ecnt) {
  int i = blockIdx.x * blockDim.x + threadIdx.x;
  if (i < e) atomicAdd(&ecnt[dst[i]], 1);
}

// per-block exclusive scan (256 elems/block); block totals to bsum
__global__ void k_scan1(const int* ecnt, int n, int* rowStart, int* bsum) {
  __shared__ int s[256];
  int t = threadIdx.x;
  int idx = blockIdx.x * 256 + t;
  int v = (idx < n) ? ecnt[idx] : 0;
  s[t] = v;
  __syncthreads();
  for (int off = 1; off < 256; off <<= 1) {
    int x = (t >= off) ? s[t - off] : 0;
    __syncthreads();
    s[t] += x;
    __syncthreads();
  }
  if (idx < n) rowStart[idx] = s[t] - v;
  if (t == 255) bsum[blockIdx.x] = s[255];
}

// single-block exclusive scan over block sums (nb <= 512)
__global__ void k_scan2(int* bsum, int nb) {
  __shared__ int s[512];
  int t = threadIdx.x;
  int v = (t < nb) ? bsum[t] : 0;
  s[t] = v;
  __syncthreads();
  for (int off = 1; off < 512; off <<= 1) {
    int x = (t >= off) ? s[t - off] : 0;
    __syncthreads();
    s[t] += x;
    __syncthreads();
  }
  if (t < nb) bsum[t] = s[t] - v;
}

__global__ void k_scan3(int* rowStart, const int* bsum, const int* ecnt, int n) {
  int i = blockIdx.x * blockDim.x + threadIdx.x;
  if (i < n) {
    int val = rowStart[i] + bsum[i >> 8];
    rowStart[i] = val;
    if (i == n - 1) rowStart[n] = val + ecnt[i];
  }
}

__global__ void k_dinv(const int* ecnt, float* dinv, int n) {
  int i = blockIdx.x * blockDim.x + threadIdx.x;
  if (i < n) dinv[i] = rsqrtf((float)(ecnt[i] + 1));  // +1 self loop
}

__global__ void k_fill(const int* src, const int* dst, int e, const int* rowStart,
                       int* cnt, int* csr) {
  int i = blockIdx.x * blockDim.x + threadIdx.x;
  if (i < e) {
    int d = dst[i];
    int pos = rowStart[d] + atomicAdd(&cnt[d], 1);
    csr[pos] = src[i];
  }
}

__global__ void k_cast(const float* x, bf16* y, long long n) {
  long long i = (long long)blockIdx.x * blockDim.x + threadIdx.x;
  if (i < n) y[i] = f2b(x[i]);
}

// ---------------- GEMM: C[N,M] = A[N,K](bf16) * B[K,M](f32), bf16 out --------

#define TS 64
#define KT 16
__global__ __launch_bounds__(256) void gemm_bf16(const bf16* __restrict__ A,
                                                 const float* __restrict__ B,
                                                 bf16* __restrict__ C,
                                                 int Nrows, int K, int M) {
  __shared__ float As[TS][KT + 1];
  __shared__ float Bs[KT][TS + 1];
  int tx = threadIdx.x & 15, ty = threadIdx.x >> 4;
  int rowBase = blockIdx.x * TS;
  int colBase = blockIdx.y * TS;
  float acc[4][4] = {};
  for (int kt = 0; kt < K; kt += KT) {
    for (int i = threadIdx.x; i < TS * KT; i += 256) {
      int r = i / KT, c = i % KT;
      int gr = rowBase + r;
      As[r][c] = (gr < Nrows) ? b2f(A[(size_t)gr * K + kt + c]) : 0.f;
    }
    for (int i = threadIdx.x; i < KT * TS; i += 256) {
      int r = i / TS, c = i % TS;
      Bs[r][c] = B[(size_t)(kt + r) * M + colBase + c];
    }
    __syncthreads();
#pragma unroll
    for (int k = 0; k < KT; ++k) {
      float a0 = As[ty * 4 + 0][k], a1 = As[ty * 4 + 1][k];
      float a2 = As[ty * 4 + 2][k], a3 = As[ty * 4 + 3][k];
      float bb0 = Bs[k][tx * 4 + 0], bb1 = Bs[k][tx * 4 + 1];
      float bb2 = Bs[k][tx * 4 + 2], bb3 = Bs[k][tx * 4 + 3];
      acc[0][0] += a0 * bb0; acc[0][1] += a0 * bb1; acc[0][2] += a0 * bb2; acc[0][3] += a0 * bb3;
      acc[1][0] += a1 * bb0; acc[1][1] += a1 * bb1; acc[1][2] += a1 * bb2; acc[1][3] += a1 * bb3;
      acc[2][0] += a2 * bb0; acc[2][1] += a2 * bb1; acc[2][2] += a2 * bb2; acc[2][3] += a2 * bb3;
      acc[3][0] += a3 * bb0; acc[3][1] += a3 * bb1; acc[3][2] += a3 * bb2; acc[3][3] += a3 * bb3;
    }
    __syncthreads();
  }
  for (int i = 0; i < 4; ++i) {
    int gr = rowBase + ty * 4 + i;
    if (gr < Nrows) {
      for (int j = 0; j < 4; ++j)
        C[(size_t)gr * M + colBase + tx * 4 + j] = f2b(acc[i][j]);
    }
  }
}

// ---------------- aggregation: out[d] = sum_{s in N(d)} dinv[s]*dinv[d]*h2[s]
//                  + dinv[d]^2 * h2[d] + bias; optional relu ----------------

__global__ void aggregate(const bf16* __restrict__ h2, const int* __restrict__ csr,
                          const int* __restrict__ rowStart, const float* __restrict__ dinv,
                          const float* __restrict__ bias, bf16* __restrict__ out,
                          int D, int relu) {
  int d = blockIdx.x;
  int t = threadIdx.x;
  float dv = dinv[d];
  float acc = b2f(h2[(size_t)d * D + t]) * dv * dv;  // self loop
  int rs = rowStart[d], re = rowStart[d + 1];
  for (int i = rs; i < re; ++i) {
    int s = csr[i];
    float w = dinv[s] * dv;
    acc += b2f(h2[(size_t)s * D + t]) * w;
  }
  acc += bias[t];
  if (relu) acc = fmaxf(acc, 0.f);
  out[(size_t)d * D + t] = f2b(acc);
}

// ---------------- pooling ----------------

__global__ void graph_bounds(const int* batch, int n, int g_cnt, int* gstart) {
  int g = blockIdx.x * blockDim.x + threadIdx.x;
  if (g > g_cnt) return;
  int lo = 0, hi = n;
  while (lo < hi) {
    int mid = (lo + hi) >> 1;
    if (batch[mid] < g) lo = mid + 1; else hi = mid;
  }
  gstart[g] = lo;
}

__global__ void pool(const bf16* __restrict__ h, const int* __restrict__ gstart,
                     float* __restrict__ gout, int D) {
  int g = blockIdx.x;
  int t = threadIdx.x;
  int s = gstart[g], e = gstart[g + 1];
  float acc = 0.f;
  for (int i = s; i < e; ++i) acc += b2f(h[(size_t)i * D + t]);
  float c = (float)((e - s) > 0 ? (e - s) : 1);
  gout[g * D + t] = acc / c;
}

// ---------------- MLP head ----------------

__global__ __launch_bounds__(256) void mlp(const float* __restrict__ g,
                                           const float* __restrict__ Wf1,
                                           const float* __restrict__ bf1,
                                           const float* __restrict__ Wf2,
                                           const float* __restrict__ bf2,
                                           float* __restrict__ out) {
  __shared__ float gs[128];
  __shared__ float hid[256];
  int b = blockIdx.x, t = threadIdx.x;
  if (t < 128) gs[t] = g[b * 128 + t];
  __syncthreads();
  float acc = bf1[t];
  for (int k = 0; k < 128; ++k) acc += gs[k] * Wf1[k * 256 + t];
  acc = fmaxf(acc, 0.f);
  hid[t] = acc * Wf2[t];
  __syncthreads();
  for (int s2 = 128; s2 > 0; s2 >>= 1) {
    if (t < s2) hid[t] += hid[t + s2];
    __syncthreads();
  }
  if (t == 0) out[b] = 1.f / (1.f + expf(-(hid[0] + bf2[0])));
}

// ---------------- launch ----------------

extern "C" void kernel_launch(void* const* d_in, const int* in_sizes, int n_in,
                              void* d_out, int out_size, void* d_ws, size_t ws_size,
                              hipStream_t stream) {
  const float* x  = (const float*)d_in[0];
  const int* ei   = (const int*)d_in[1];
  const int* batch = (const int*)d_in[2];
  const float* W0 = (const float*)d_in[3];
  const float* b0 = (const float*)d_in[4];
  const float* W1 = (const float*)d_in[5];
  const float* b1 = (const float*)d_in[6];
  const float* W2 = (const float*)d_in[7];
  const float* b2 = (const float*)d_in[8];
  const float* Wf1 = (const float*)d_in[9];
  const float* bf1 = (const float*)d_in[10];
  const float* Wf2 = (const float*)d_in[11];
  const float* bf2 = (const float*)d_in[12];
  float* out = (float*)d_out;

  const int DIN = 128, DH = 256, DOUT = 128, G = 128;
  const int N = in_sizes[0] / DIN;
  const int E = in_sizes[1] / 2;
  const int* src = ei;
  const int* dst = ei + E;

  char* p = (char*)d_ws;
  auto alloc = [&](size_t bytes) {
    char* r = p;
    p += (bytes + 255) & ~(size_t)255;
    return r;
  };
  int* ecnt      = (int*)alloc((size_t)N * 4);
  int* cnt       = (int*)alloc((size_t)N * 4);
  int* rowStart  = (int*)alloc((size_t)(N + 1) * 4);
  int* bsum      = (int*)alloc(4096);
  float* dinv    = (float*)alloc((size_t)N * 4);
  int* csr       = (int*)alloc((size_t)E * 4);
  int* gstart    = (int*)alloc((size_t)(G + 1) * 4);
  float* gbuf    = (float*)alloc((size_t)G * DOUT * 4);
  bf16* bufA     = (bf16*)alloc((size_t)N * DH * 2);
  bf16* bufB     = (bf16*)alloc((size_t)N * DH * 2);

  const int tb = 256;
  k_init<<<(N + tb - 1) / tb, tb, 0, stream>>>(ecnt, cnt, N);
  k_hist<<<(E + tb - 1) / tb, tb, 0, stream>>>(dst, E, ecnt);
  int nb = (N + 255) / 256;
  k_scan1<<<nb, 256, 0, stream>>>(ecnt, N, rowStart, bsum);
  k_scan2<<<1, 512, 0, stream>>>(bsum, nb);
  k_scan3<<<(N + tb - 1) / tb, tb, 0, stream>>>(rowStart, bsum, ecnt, N);
  k_dinv<<<(N + tb - 1) / tb, tb, 0, stream>>>(ecnt, dinv, N);
  k_fill<<<(E + tb - 1) / tb, tb, 0, stream>>>(src, dst, E, rowStart, cnt, csr);

  long long xn = (long long)N * DIN;
  k_cast<<<(int)((xn + tb - 1) / tb), tb, 0, stream>>>(x, bufA, xn);

  dim3 g1((N + TS - 1) / TS, DH / TS);
  gemm_bf16<<<g1, 256, 0, stream>>>(bufA, W0, bufB, N, DIN, DH);
  aggregate<<<N, DH, 0, stream>>>(bufB, csr, rowStart, dinv, b0, bufA, DH, 1);
  gemm_bf16<<<g1, 256, 0, stream>>>(bufA, W1, bufB, N, DH, DH);
  aggregate<<<N, DH, 0, stream>>>(bufB, csr, rowStart, dinv, b1, bufA, DH, 1);
  dim3 g3((N + TS - 1) / TS, DOUT / TS);
  gemm_bf16<<<g3, 256, 0, stream>>>(bufA, W2, bufB, N, DH, DOUT);
  aggregate<<<N, DOUT, 0, stream>>>(bufB, csr, rowStart, dinv, b2, bufA, DOUT, 0);

  graph_bounds<<<1, 256, 0, stream>>>(batch, N, G, gstart);
  pool<<<G, DOUT, 0, stream>>>(bufA, gstart, gbuf, DOUT);
  mlp<<<G, 256, 0, stream>>>(gbuf, Wf1, bf1, Wf2, bf2, out);
}

// Round 2
// 584.344 us; speedup vs baseline: 3.0761x; 3.0761x over previous
//
#include <hip/hip_runtime.h>
#include <hip/hip_bf16.h>

typedef __hip_bfloat16 hbf16;
typedef __attribute__((ext_vector_type(8))) short short8;
typedef __attribute__((ext_vector_type(4))) float f32x4;

static __device__ __forceinline__ float bits2f(unsigned short u) {
  return __uint_as_float(((unsigned)u) << 16);
}
static __device__ __forceinline__ unsigned short f2bits(float f) {
  hbf16 h = __float2bfloat16(f);
  return *reinterpret_cast<unsigned short*>(&h);
}

// ---------------- preprocessing ----------------

__global__ void k_init(int* ecnt, int* cnt, int n) {
  int i = blockIdx.x * blockDim.x + threadIdx.x;
  if (i < n) { ecnt[i] = 0; cnt[i] = 0; }
}

__global__ void k_hist(const int* dst, int e, int* ecnt) {
  int i = blockIdx.x * blockDim.x + threadIdx.x;
  if (i < e) atomicAdd(&ecnt[dst[i]], 1);
}

__global__ void k_scan1(const int* ecnt, int n, int* rowStart, int* bsum) {
  __shared__ int s[256];
  int t = threadIdx.x;
  int idx = blockIdx.x * 256 + t;
  int v = (idx < n) ? ecnt[idx] : 0;
  s[t] = v;
  __syncthreads();
  for (int off = 1; off < 256; off <<= 1) {
    int x = (t >= off) ? s[t - off] : 0;
    __syncthreads();
    s[t] += x;
    __syncthreads();
  }
  if (idx < n) rowStart[idx] = s[t] - v;
  if (t == 255) bsum[blockIdx.x] = s[255];
}

__global__ void k_scan2(int* bsum, int nb) {
  __shared__ int s[512];
  int t = threadIdx.x;
  int v = (t < nb) ? bsum[t] : 0;
  s[t] = v;
  __syncthreads();
  for (int off = 1; off < 512; off <<= 1) {
    int x = (t >= off) ? s[t - off] : 0;
    __syncthreads();
    s[t] += x;
    __syncthreads();
  }
  if (t < nb) bsum[t] = s[t] - v;
}

__global__ void k_scan3(int* rowStart, const int* bsum, const int* ecnt, int n) {
  int i = blockIdx.x * blockDim.x + threadIdx.x;
  if (i < n) {
    int val = rowStart[i] + bsum[i >> 8];
    rowStart[i] = val;
    if (i == n - 1) rowStart[n] = val + ecnt[i];
  }
}

__global__ void k_dinv(const int* ecnt, float* dinv, int n) {
  int i = blockIdx.x * blockDim.x + threadIdx.x;
  if (i < n) dinv[i] = rsqrtf((float)(ecnt[i] + 1));
}

__global__ void k_fill(const int* src, const int* dst, int e, const int* rowStart,
                       int* cnt, int* csr) {
  int i = blockIdx.x * blockDim.x + threadIdx.x;
  if (i < e) {
    int d = dst[i];
    int pos = rowStart[d] + atomicAdd(&cnt[d], 1);
    csr[pos] = src[i];
  }
}

// transpose + cast weights: Wt[m*K + k] = bf16(W[k*M + m])
__global__ void k_wt(const float* W, unsigned short* Wt, int K, int M) {
  int i = blockIdx.x * blockDim.x + threadIdx.x;
  if (i < K * M) {
    int m = i / K, k = i - m * K;
    Wt[i] = f2bits(W[k * M + m]);
  }
}

__global__ void k_cast4(const float* __restrict__ x, unsigned short* __restrict__ y, int n4) {
  int i = blockIdx.x * blockDim.x + threadIdx.x;
  if (i < n4) {
    float4 v = reinterpret_cast<const float4*>(x)[i];
    ushort4 o;
    o.x = f2bits(v.x); o.y = f2bits(v.y); o.z = f2bits(v.z); o.w = f2bits(v.w);
    reinterpret_cast<ushort4*>(y)[i] = o;
  }
}

__global__ void k_zerof(float* p, int n) {
  int i = blockIdx.x * blockDim.x + threadIdx.x;
  if (i < n) p[i] = 0.f;
}

// ---------------- aggregation (LDS-staged meta, short8 gathers) --------------
// out[d] = sum_{s in N(d)} dinv[s]*dinv[d]*h[s] + dinv[d]^2*h[d] (+bias)

template<int D, int BIAS>
__global__ __launch_bounds__(256) void aggregate(
    const unsigned short* __restrict__ h, const int* __restrict__ csr,
    const int* __restrict__ rowStart, const float* __restrict__ dinv,
    const float* __restrict__ bias, unsigned short* __restrict__ out, int N) {
  constexpr int TPN = D / 8;        // threads per node (16B each)
  constexpr int NB = 256 / TPN;     // nodes per block
  constexpr int CH = 64;            // neighbor chunk
  __shared__ int s_idx[NB * CH];
  __shared__ float s_w[NB * CH];
  __shared__ int s_rs[NB], s_cnt[NB];
  __shared__ float s_dv[NB];

  int tid = threadIdx.x;
  int d0 = blockIdx.x * NB;
  if (tid < NB) {
    int d = d0 + tid;
    if (d < N) {
      int rs = rowStart[d], re = rowStart[d + 1];
      s_rs[tid] = rs; s_cnt[tid] = re - rs; s_dv[tid] = dinv[d];
    } else {
      s_rs[tid] = 0; s_cnt[tid] = 0; s_dv[tid] = 1.f;
    }
  }
  __syncthreads();
  int maxc = 0;
#pragma unroll
  for (int i = 0; i < NB; ++i) maxc = max(maxc, s_cnt[i]);

  int nd = tid / TPN, te = tid - nd * TPN;
  int d = d0 + nd;
  int dc = min(d, N - 1);
  float dv = s_dv[nd];

  float acc[8];
  {
    short8 sv = *reinterpret_cast<const short8*>(h + (size_t)dc * D + te * 8);
    float w = dv * dv;
#pragma unroll
    for (int j = 0; j < 8; ++j) acc[j] = w * bits2f((unsigned short)sv[j]);
  }

  for (int base = 0; base < maxc; base += CH) {
    for (int j = tid; j < NB * CH; j += 256) {
      int n2 = j / CH, k2 = j - n2 * CH;
      if (k2 < s_cnt[n2] - base) {
        int s = csr[s_rs[n2] + base + k2];
        s_idx[j] = s;
        s_w[j] = dinv[s] * s_dv[n2];
      }
    }
    __syncthreads();
    int kmax = min(CH, s_cnt[nd] - base);
    if (kmax < 0) kmax = 0;
    const int mb = nd * CH;
    int k = 0;
    for (; k + 4 <= kmax; k += 4) {
      int i0 = s_idx[mb + k], i1 = s_idx[mb + k + 1], i2 = s_idx[mb + k + 2], i3 = s_idx[mb + k + 3];
      float w0 = s_w[mb + k], w1 = s_w[mb + k + 1], w2 = s_w[mb + k + 2], w3 = s_w[mb + k + 3];
      short8 v0 = *reinterpret_cast<const short8*>(h + (size_t)i0 * D + te * 8);
      short8 v1 = *reinterpret_cast<const short8*>(h + (size_t)i1 * D + te * 8);
      short8 v2 = *reinterpret_cast<const short8*>(h + (size_t)i2 * D + te * 8);
      short8 v3 = *reinterpret_cast<const short8*>(h + (size_t)i3 * D + te * 8);
#pragma unroll
      for (int j = 0; j < 8; ++j) {
        acc[j] += w0 * bits2f((unsigned short)v0[j]);
        acc[j] += w1 * bits2f((unsigned short)v1[j]);
        acc[j] += w2 * bits2f((unsigned short)v2[j]);
        acc[j] += w3 * bits2f((unsigned short)v3[j]);
      }
    }
    for (; k < kmax; ++k) {
      int s = s_idx[mb + k];
      float w = s_w[mb + k];
      short8 v = *reinterpret_cast<const short8*>(h + (size_t)s * D + te * 8);
#pragma unroll
      for (int j = 0; j < 8; ++j) acc[j] += w * bits2f((unsigned short)v[j]);
    }
    __syncthreads();
  }

  if (d < N) {
    short8 o;
#pragma unroll
    for (int j = 0; j < 8; ++j) {
      float v = acc[j];
      if (BIAS) v += bias[te * 8 + j];
      o[j] = (short)f2bits(v);
    }
    *reinterpret_cast<short8*>(out + (size_t)d * D + te * 8) = o;
  }
}

// ---------------- MFMA GEMM: C[N,M] = A[N,K] * Bt[M,K]^T, bf16 in/out --------
// 128x128 tile, BK=64, 4 waves each 64x64, global_load_lds(16) with
// pre-swizzled source + XOR-swizzled ds_read_b128 (involution both sides).

#define GLD16(g, l) __builtin_amdgcn_global_load_lds(                         \
    (const __attribute__((address_space(1))) void*)(g),                       \
    (__attribute__((address_space(3))) void*)(l), 16, 0, 0)

template<int K, int EPI>  // EPI: 0 = none, 1 = bias+relu
__global__ __launch_bounds__(256) void gemm_mfma(
    const unsigned short* __restrict__ A, const unsigned short* __restrict__ Bt,
    const float* __restrict__ bias, unsigned short* __restrict__ C,
    int N, int M) {
  __shared__ __align__(16) char smem[32768];
  char* lA = smem;
  char* lB = smem + 16384;
  int tid = threadIdx.x, lane = tid & 63, wid = tid >> 6;
  int rowBase = blockIdx.x * 128, colBase = blockIdx.y * 128;
  int wr = (wid >> 1) * 64, wc = (wid & 1) * 64;

  f32x4 zero = {0.f, 0.f, 0.f, 0.f};
  f32x4 acc[4][4];
#pragma unroll
  for (int m = 0; m < 4; ++m)
#pragma unroll
    for (int n = 0; n < 4; ++n) acc[m][n] = zero;

  const char* Ab = (const char*)A;
  const char* Bb = (const char*)Bt;

  for (int k0 = 0; k0 < K; k0 += 64) {
#pragma unroll
    for (int r = 0; r < 4; ++r) {
      int pbase = r * 256 + wid * 64;
      int p = pbase + lane;
      int row = p >> 3;                                 // tile-local row 0..127
      int offg = ((p & 7) * 16) ^ ((row & 7) << 4);     // pre-swizzled source
      int ga = min(rowBase + row, N - 1);
      GLD16(Ab + (size_t)ga * (K * 2) + k0 * 2 + offg, lA + pbase * 16);
      int gb = colBase + row;                           // always < M
      GLD16(Bb + (size_t)gb * (K * 2) + k0 * 2 + offg, lB + pbase * 16);
    }
    __syncthreads();
    int l15 = lane & 15, lhi = lane >> 4;
#pragma unroll
    for (int kk = 0; kk < 2; ++kk) {
      short8 af[4], bfr[4];
      int koff = kk * 64 + lhi * 16;
#pragma unroll
      for (int m = 0; m < 4; ++m) {
        int row = wr + m * 16 + l15;
        af[m] = *reinterpret_cast<const short8*>(lA + row * 128 + (koff ^ ((row & 7) << 4)));
      }
#pragma unroll
      for (int n = 0; n < 4; ++n) {
        int col = wc + n * 16 + l15;
        bfr[n] = *reinterpret_cast<const short8*>(lB + col * 128 + (koff ^ ((col & 7) << 4)));
      }
#pragma unroll
      for (int m = 0; m < 4; ++m)
#pragma unroll
        for (int n = 0; n < 4; ++n)
          acc[m][n] = __builtin_amdgcn_mfma_f32_16x16x32_bf16(af[m], bfr[n], acc[m][n], 0, 0, 0);
    }
    __syncthreads();
  }

  int l15 = lane & 15, lhi = lane >> 4;
#pragma unroll
  for (int n = 0; n < 4; ++n) {
    int col = colBase + wc + n * 16 + l15;
    float bv = (EPI == 1) ? bias[col] : 0.f;
#pragma unroll
    for (int m = 0; m < 4; ++m) {
#pragma unroll
      for (int r = 0; r < 4; ++r) {
        int row = rowBase + wr + m * 16 + lhi * 4 + r;
        if (row < N) {
          float v = acc[m][n][r] + bv;
          if (EPI == 1) v = fmaxf(v, 0.f);
          C[(size_t)row * M + col] = f2bits(v);
        }
      }
    }
  }
}

// ---------------- pooling ----------------

__global__ void graph_bounds(const int* batch, int n, int g_cnt, int* gstart) {
  int g = blockIdx.x * blockDim.x + threadIdx.x;
  if (g > g_cnt) return;
  int lo = 0, hi = n;
  while (lo < hi) {
    int mid = (lo + hi) >> 1;
    if (batch[mid] < g) lo = mid + 1; else hi = mid;
  }
  gstart[g] = lo;
}

__global__ void pool_partial(const unsigned short* __restrict__ h,
                             const int* __restrict__ batch, int N, float* gbuf) {
  int per = (N + gridDim.x - 1) / gridDim.x;
  int lo = blockIdx.x * per;
  int hi = min(N, lo + per);
  if (lo >= hi) return;
  int t = threadIdx.x;
  int cur = batch[lo];
  float acc = 0.f;
  for (int i = lo; i < hi; ++i) {
    int g = batch[i];
    if (g != cur) {
      atomicAdd(&gbuf[cur * 128 + t], acc);
      acc = 0.f;
      cur = g;
    }
    acc += bits2f(h[(size_t)i * 128 + t]);
  }
  atomicAdd(&gbuf[cur * 128 + t], acc);
}

// ---------------- MLP head ----------------

__global__ __launch_bounds__(256) void mlp(const float* __restrict__ gbuf,
                                           const int* __restrict__ gstart,
                                           const float* __restrict__ Wf1,
                                           const float* __restrict__ bf1,
                                           const float* __restrict__ Wf2,
                                           const float* __restrict__ bf2,
                                           float* __restrict__ out) {
  __shared__ float gs[128];
  __shared__ float hid[256];
  int b = blockIdx.x, t = threadIdx.x;
  float inv = 1.f / (float)max(gstart[b + 1] - gstart[b], 1);
  if (t < 128) gs[t] = gbuf[b * 128 + t] * inv;
  __syncthreads();
  float acc = bf1[t];
  for (int k = 0; k < 128; ++k) acc += gs[k] * Wf1[k * 256 + t];
  acc = fmaxf(acc, 0.f);
  hid[t] = acc * Wf2[t];
  __syncthreads();
  for (int s2 = 128; s2 > 0; s2 >>= 1) {
    if (t < s2) hid[t] += hid[t + s2];
    __syncthreads();
  }
  if (t == 0) out[b] = 1.f / (1.f + expf(-(hid[0] + bf2[0])));
}

// ---------------- launch ----------------

extern "C" void kernel_launch(void* const* d_in, const int* in_sizes, int n_in,
                              void* d_out, int out_size, void* d_ws, size_t ws_size,
                              hipStream_t stream) {
  const float* x   = (const float*)d_in[0];
  const int* ei    = (const int*)d_in[1];
  const int* batch = (const int*)d_in[2];
  const float* W0  = (const float*)d_in[3];
  const float* b0  = (const float*)d_in[4];
  const float* W1  = (const float*)d_in[5];
  const float* b1  = (const float*)d_in[6];
  const float* W2  = (const float*)d_in[7];
  const float* b2  = (const float*)d_in[8];
  const float* Wf1 = (const float*)d_in[9];
  const float* bf1 = (const float*)d_in[10];
  const float* Wf2 = (const float*)d_in[11];
  const float* bf2 = (const float*)d_in[12];
  float* out = (float*)d_out;

  const int DIN = 128, DH = 256, DOUT = 128, G = 128;
  const int N = in_sizes[0] / DIN;
  const int E = in_sizes[1] / 2;
  const int* src = ei;
  const int* dst = ei + E;

  char* p = (char*)d_ws;
  auto alloc = [&](size_t bytes) {
    char* r = p;
    p += (bytes + 255) & ~(size_t)255;
    return r;
  };
  int* ecnt     = (int*)alloc((size_t)N * 4);
  int* cnt      = (int*)alloc((size_t)N * 4);
  int* rowStart = (int*)alloc((size_t)(N + 1) * 4);
  int* bsum     = (int*)alloc(4096);
  float* dinv   = (float*)alloc((size_t)N * 4);
  int* csr      = (int*)alloc((size_t)E * 4);
  int* gstart   = (int*)alloc((size_t)(G + 1) * 4);
  float* gbuf   = (float*)alloc((size_t)G * DOUT * 4);
  unsigned short* W0t = (unsigned short*)alloc((size_t)DIN * DH * 2);
  unsigned short* W1t = (unsigned short*)alloc((size_t)DH * DH * 2);
  unsigned short* W2t = (unsigned short*)alloc((size_t)DH * DOUT * 2);
  unsigned short* B256a = (unsigned short*)alloc((size_t)N * DH * 2);
  unsigned short* B256b = (unsigned short*)alloc((size_t)N * DH * 2);

  unsigned short* xb     = B256a;                      // [N,128]
  unsigned short* agg0   = B256b;                      // [N,128]
  unsigned short* h1     = B256a;                      // [N,256]
  unsigned short* agg1   = B256b;                      // [N,256]
  unsigned short* h2     = B256a;                      // [N,256]
  unsigned short* t2     = B256b;                      // [N,128]
  unsigned short* aggout = B256b + (size_t)N * DOUT;   // [N,128]

  const int tb = 256;
  k_init<<<(N + tb - 1) / tb, tb, 0, stream>>>(ecnt, cnt, N);
  k_hist<<<(E + tb - 1) / tb, tb, 0, stream>>>(dst, E, ecnt);
  int nb = (N + 255) / 256;
  k_scan1<<<nb, 256, 0, stream>>>(ecnt, N, rowStart, bsum);
  k_scan2<<<1, 512, 0, stream>>>(bsum, nb);
  k_scan3<<<(N + tb - 1) / tb, tb, 0, stream>>>(rowStart, bsum, ecnt, N);
  k_dinv<<<(N + tb - 1) / tb, tb, 0, stream>>>(ecnt, dinv, N);
  k_fill<<<(E + tb - 1) / tb, tb, 0, stream>>>(src, dst, E, rowStart, cnt, csr);

  k_wt<<<(DIN * DH + tb - 1) / tb, tb, 0, stream>>>(W0, W0t, DIN, DH);
  k_wt<<<(DH * DH + tb - 1) / tb, tb, 0, stream>>>(W1, W1t, DH, DH);
  k_wt<<<(DH * DOUT + tb - 1) / tb, tb, 0, stream>>>(W2, W2t, DH, DOUT);

  int n4 = N * DIN / 4;
  k_cast4<<<(n4 + tb - 1) / tb, tb, 0, stream>>>(x, xb, n4);

  int gx = (N + 127) / 128;

  // layer 0: aggregate-first (D=128), then GEMM 128->256 + bias + relu
  aggregate<128, 0><<<(N + 15) / 16, 256, 0, stream>>>(xb, csr, rowStart, dinv, nullptr, agg0, N);
  gemm_mfma<128, 1><<<dim3(gx, 2), 256, 0, stream>>>(agg0, W0t, b0, h1, N, DH);

  // layer 1: aggregate-first (D=256), then GEMM 256->256 + bias + relu
  aggregate<256, 0><<<(N + 7) / 8, 256, 0, stream>>>(h1, csr, rowStart, dinv, nullptr, agg1, N);
  gemm_mfma<256, 1><<<dim3(gx, 2), 256, 0, stream>>>(agg1, W1t, b1, h2, N, DH);

  // layer 2: GEMM 256->128 (no bias), then aggregate (D=128) + bias
  gemm_mfma<256, 0><<<dim3(gx, 1), 256, 0, stream>>>(h2, W2t, nullptr, t2, N, DOUT);
  aggregate<128, 1><<<(N + 15) / 16, 256, 0, stream>>>(t2, csr, rowStart, dinv, b2, aggout, N);

  graph_bounds<<<1, 256, 0, stream>>>(batch, N, G, gstart);
  k_zerof<<<(G * DOUT + tb - 1) / tb, tb, 0, stream>>>(gbuf, G * DOUT);
  pool_partial<<<1000, 128, 0, stream>>>(aggout, batch, N, gbuf);
  mlp<<<G, 256, 0, stream>>>(gbuf, gstart, Wf1, bf1, Wf2, bf2, out);
}